// Round 1
// baseline (1018.090 us; speedup 1.0000x reference)
//
#include <hip/hip_runtime.h>

// DiffeomorphicTransform2: scaling-and-squaring integration of a stationary
// velocity field. flow: [1, 3, 160, 192, 160] float32.
//   f = flow / 2^7
//   repeat 7x: f = f + trilinear_sample(f, base_grid + disp(f))
// disp channel mapping: coords.x (W axis) <- ch2, coords.y (H) <- ch1,
// coords.z (D) <- ch0. Border clamp, align_corners=True.
//
// One kernel launch per step (gathers require a grid-wide barrier between
// steps). Ping-pong: step1 d_in->d_out (with 1/128 scale fused into every
// read -- legal since trilinear sampling is linear in volume values),
// step2 d_out->d_ws, ... step7 d_ws->d_out. 7 steps (odd) lands in d_out.

#define DD 160
#define HH 192
#define WW 160
#define NVOX (DD * HH * WW)   // 4,915,200 ; divisible by 256 (19200 blocks)

__global__ __launch_bounds__(256) void diffeo_step(const float* __restrict__ in,
                                                   float* __restrict__ out,
                                                   float scale) {
    const int tid = blockIdx.x * 256 + threadIdx.x;   // NVOX % 256 == 0
    const int w = tid % WW;
    const int t = tid / WW;
    const int h = t % HH;
    const int d = t / HH;

    // center values (channel-major layout [C, N]); scale fuses the initial /128
    const float f0 = in[tid] * scale;              // z-displacement (ch0)
    const float f1 = in[NVOX + tid] * scale;       // y-displacement (ch1)
    const float f2 = in[2 * NVOX + tid] * scale;   // x-displacement (ch2)

    // normalized base grid (align_corners=True linspace(-1,1,n))
    const float gx = -1.0f + 2.0f * (float)w / (float)(WW - 1);
    const float gy = -1.0f + 2.0f * (float)h / (float)(HH - 1);
    const float gz = -1.0f + 2.0f * (float)d / (float)(DD - 1);

    // unnormalize + border clamp
    float x = (gx + f2 + 1.0f) * (0.5f * (float)(WW - 1));
    float y = (gy + f1 + 1.0f) * (0.5f * (float)(HH - 1));
    float z = (gz + f0 + 1.0f) * (0.5f * (float)(DD - 1));
    x = fminf(fmaxf(x, 0.0f), (float)(WW - 1));
    y = fminf(fmaxf(y, 0.0f), (float)(HH - 1));
    z = fminf(fmaxf(z, 0.0f), (float)(DD - 1));

    const float x0f = floorf(x), y0f = floorf(y), z0f = floorf(z);
    const float wx = x - x0f, wy = y - y0f, wz = z - z0f;
    const int x0 = (int)x0f, y0 = (int)y0f, z0 = (int)z0f;
    const int x1 = min(x0 + 1, WW - 1);
    const int y1 = min(y0 + 1, HH - 1);
    const int z1 = min(z0 + 1, DD - 1);

    const int b00 = (z0 * HH + y0) * WW;
    const int b01 = (z0 * HH + y1) * WW;
    const int b10 = (z1 * HH + y0) * WW;
    const int b11 = (z1 * HH + y1) * WW;
    const int i000 = b00 + x0, i001 = b00 + x1;
    const int i010 = b01 + x0, i011 = b01 + x1;
    const int i100 = b10 + x0, i101 = b10 + x1;
    const int i110 = b11 + x0, i111 = b11 + x1;

    const float omx = 1.0f - wx, omy = 1.0f - wy, omz = 1.0f - wz;
    const float w000 = omz * omy * omx;
    const float w001 = omz * omy * wx;
    const float w010 = omz * wy * omx;
    const float w011 = omz * wy * wx;
    const float w100 = wz * omy * omx;
    const float w101 = wz * omy * wx;
    const float w110 = wz * wy * omx;
    const float w111 = wz * wy * wx;

    // issue all 24 gathers up front for memory-level parallelism
    const float* v0 = in;
    const float* v1 = in + NVOX;
    const float* v2 = in + 2 * NVOX;

    const float a000 = v0[i000], a001 = v0[i001], a010 = v0[i010], a011 = v0[i011];
    const float a100 = v0[i100], a101 = v0[i101], a110 = v0[i110], a111 = v0[i111];
    const float b000 = v1[i000], b001 = v1[i001], b010 = v1[i010], b011 = v1[i011];
    const float b100 = v1[i100], b101 = v1[i101], b110 = v1[i110], b111 = v1[i111];
    const float c000 = v2[i000], c001 = v2[i001], c010 = v2[i010], c011 = v2[i011];
    const float c100 = v2[i100], c101 = v2[i101], c110 = v2[i110], c111 = v2[i111];

    float s0 = a000 * w000 + a001 * w001 + a010 * w010 + a011 * w011
             + a100 * w100 + a101 * w101 + a110 * w110 + a111 * w111;
    float s1 = b000 * w000 + b001 * w001 + b010 * w010 + b011 * w011
             + b100 * w100 + b101 * w101 + b110 * w110 + b111 * w111;
    float s2 = c000 * w000 + c001 * w001 + c010 * w010 + c011 * w011
             + c100 * w100 + c101 * w101 + c110 * w110 + c111 * w111;

    out[tid]            = f0 + s0 * scale;
    out[NVOX + tid]     = f1 + s1 * scale;
    out[2 * NVOX + tid] = f2 + s2 * scale;
}

extern "C" void kernel_launch(void* const* d_in, const int* in_sizes, int n_in,
                              void* d_out, int out_size, void* d_ws, size_t ws_size,
                              hipStream_t stream) {
    const float* flow = (const float*)d_in[0];
    float* out = (float*)d_out;
    float* ws  = (float*)d_ws;

    const int nblk = NVOX / 256;   // 19200
    const float inv128 = 1.0f / 128.0f;   // 1 / 2^TIME_STEP

    // step 1: d_in -> d_out (fused /128 on every read)
    diffeo_step<<<nblk, 256, 0, stream>>>(flow, out, inv128);
    // steps 2..7: ping-pong out <-> ws; odd total lands in d_out
    diffeo_step<<<nblk, 256, 0, stream>>>(out, ws, 1.0f);
    diffeo_step<<<nblk, 256, 0, stream>>>(ws, out, 1.0f);
    diffeo_step<<<nblk, 256, 0, stream>>>(out, ws, 1.0f);
    diffeo_step<<<nblk, 256, 0, stream>>>(ws, out, 1.0f);
    diffeo_step<<<nblk, 256, 0, stream>>>(out, ws, 1.0f);
    diffeo_step<<<nblk, 256, 0, stream>>>(ws, out, 1.0f);
}

// Round 2
// 601.719 us; speedup vs baseline: 1.6920x; 1.6920x over previous
//
#include <hip/hip_runtime.h>

// DiffeomorphicTransform2: scaling-and-squaring integration of a stationary
// velocity field. flow: [1, 3, 160, 192, 160] float32.
//   f = flow / 2^7 ; repeat 7x: f = f + trilinear_sample(f, base_grid + disp(f))
// disp mapping: coords.x (W) <- ch2, coords.y (H) <- ch1, coords.z (D) <- ch0.
// Border clamp, align_corners=True.
//
// R1 -> R2 changes (FETCH_SIZE was 253 MB/step vs 59 MB ideal):
//  * channels packed as float3 per voxel for intermediate steps: 8 dwordx3
//    gathers instead of 24 dword gathers against 3 disjoint regions.
//    Pack fused into step 1, unpack fused into step 7.
//  * XCD slab swizzle: blockIdx remapped so XCD (b%8) sweeps a contiguous
//    z-slab -> per-XCD L2 stops re-fetching the whole volume.
// Ping-pong (no in-place): 1: in(planar)->out(packed); 2: out->ws; 3: ws->out;
// 4: out->ws; 5: ws->out; 6: out->ws; 7: ws(packed)->out(planar).

#define DD 160
#define HH 192
#define WW 160
#define NVOX (DD * HH * WW)     // 4,915,200
#define NBLK (NVOX / 256)       // 19200 (divisible by 8 -> 2400 blocks/XCD)

template<bool IN_PACKED, bool OUT_PACKED>
__global__ __launch_bounds__(256) void diffeo_step_t(const float* __restrict__ in,
                                                     float* __restrict__ out,
                                                     float scale) {
    // XCD-aware swizzle: physical block b presumably lands on XCD b%8;
    // give XCD k the contiguous logical slab [k*2400, (k+1)*2400).
    const int b = blockIdx.x;
    const int l = (b & 7) * (NBLK / 8) + (b >> 3);
    const int tid = l * 256 + (int)threadIdx.x;

    const int w = tid % WW;
    const int t = tid / WW;
    const int h = t % HH;
    const int d = t / HH;

    // center displacement values (ch0=z, ch1=y, ch2=x)
    float f0, f1, f2;
    if (IN_PACKED) {
        const float* p = in + 3 * tid;
        f0 = p[0]; f1 = p[1]; f2 = p[2];
    } else {
        f0 = in[tid] * scale;
        f1 = in[NVOX + tid] * scale;
        f2 = in[2 * NVOX + tid] * scale;
    }

    // normalized base grid (align_corners=True), unnormalize, border clamp
    const float gx = -1.0f + 2.0f * (float)w / (float)(WW - 1);
    const float gy = -1.0f + 2.0f * (float)h / (float)(HH - 1);
    const float gz = -1.0f + 2.0f * (float)d / (float)(DD - 1);
    float x = (gx + f2 + 1.0f) * (0.5f * (float)(WW - 1));
    float y = (gy + f1 + 1.0f) * (0.5f * (float)(HH - 1));
    float z = (gz + f0 + 1.0f) * (0.5f * (float)(DD - 1));
    x = fminf(fmaxf(x, 0.0f), (float)(WW - 1));
    y = fminf(fmaxf(y, 0.0f), (float)(HH - 1));
    z = fminf(fmaxf(z, 0.0f), (float)(DD - 1));

    const float x0f = floorf(x), y0f = floorf(y), z0f = floorf(z);
    const float wx = x - x0f, wy = y - y0f, wz = z - z0f;
    const int x0 = (int)x0f, y0 = (int)y0f, z0 = (int)z0f;
    const int x1 = min(x0 + 1, WW - 1);
    const int y1 = min(y0 + 1, HH - 1);
    const int z1 = min(z0 + 1, DD - 1);

    const int b00 = (z0 * HH + y0) * WW;
    const int b01 = (z0 * HH + y1) * WW;
    const int b10 = (z1 * HH + y0) * WW;
    const int b11 = (z1 * HH + y1) * WW;
    const int i000 = b00 + x0, i001 = b00 + x1;
    const int i010 = b01 + x0, i011 = b01 + x1;
    const int i100 = b10 + x0, i101 = b10 + x1;
    const int i110 = b11 + x0, i111 = b11 + x1;

    const float omx = 1.0f - wx, omy = 1.0f - wy, omz = 1.0f - wz;
    const float w000 = omz * omy * omx, w001 = omz * omy * wx;
    const float w010 = omz * wy * omx,  w011 = omz * wy * wx;
    const float w100 = wz * omy * omx,  w101 = wz * omy * wx;
    const float w110 = wz * wy * omx,   w111 = wz * wy * wx;

    float s0, s1, s2;
    if (IN_PACKED) {
        // 8 gathers of 12 contiguous bytes each (dwordx3), issued up front
        const float* p000 = in + 3 * i000;  const float* p001 = in + 3 * i001;
        const float* p010 = in + 3 * i010;  const float* p011 = in + 3 * i011;
        const float* p100 = in + 3 * i100;  const float* p101 = in + 3 * i101;
        const float* p110 = in + 3 * i110;  const float* p111 = in + 3 * i111;
        const float a0 = p000[0], a1 = p000[1], a2 = p000[2];
        const float b0_ = p001[0], b1_ = p001[1], b2_ = p001[2];
        const float c0 = p010[0], c1 = p010[1], c2 = p010[2];
        const float e0 = p011[0], e1 = p011[1], e2 = p011[2];
        const float g0 = p100[0], g1 = p100[1], g2 = p100[2];
        const float h0 = p101[0], h1 = p101[1], h2 = p101[2];
        const float j0 = p110[0], j1 = p110[1], j2 = p110[2];
        const float k0 = p111[0], k1 = p111[1], k2 = p111[2];
        s0 = a0*w000 + b0_*w001 + c0*w010 + e0*w011 + g0*w100 + h0*w101 + j0*w110 + k0*w111;
        s1 = a1*w000 + b1_*w001 + c1*w010 + e1*w011 + g1*w100 + h1*w101 + j1*w110 + k1*w111;
        s2 = a2*w000 + b2_*w001 + c2*w010 + e2*w011 + g2*w100 + h2*w101 + j2*w110 + k2*w111;
    } else {
        const float* v0 = in;
        const float* v1 = in + NVOX;
        const float* v2 = in + 2 * NVOX;
        const float a000 = v0[i000], a001 = v0[i001], a010 = v0[i010], a011 = v0[i011];
        const float a100 = v0[i100], a101 = v0[i101], a110 = v0[i110], a111 = v0[i111];
        const float b000 = v1[i000], b001 = v1[i001], b010 = v1[i010], b011 = v1[i011];
        const float b100 = v1[i100], b101 = v1[i101], b110 = v1[i110], b111 = v1[i111];
        const float c000 = v2[i000], c001 = v2[i001], c010 = v2[i010], c011 = v2[i011];
        const float c100 = v2[i100], c101 = v2[i101], c110 = v2[i110], c111 = v2[i111];
        s0 = (a000*w000 + a001*w001 + a010*w010 + a011*w011
            + a100*w100 + a101*w101 + a110*w110 + a111*w111) * scale;
        s1 = (b000*w000 + b001*w001 + b010*w010 + b011*w011
            + b100*w100 + b101*w101 + b110*w110 + b111*w111) * scale;
        s2 = (c000*w000 + c001*w001 + c010*w010 + c011*w011
            + c100*w100 + c101*w101 + c110*w110 + c111*w111) * scale;
    }

    const float r0 = f0 + s0;
    const float r1 = f1 + s1;
    const float r2 = f2 + s2;

    if (OUT_PACKED) {
        float* q = out + 3 * tid;
        q[0] = r0; q[1] = r1; q[2] = r2;
    } else {
        out[tid]            = r0;
        out[NVOX + tid]     = r1;
        out[2 * NVOX + tid] = r2;
    }
}

extern "C" void kernel_launch(void* const* d_in, const int* in_sizes, int n_in,
                              void* d_out, int out_size, void* d_ws, size_t ws_size,
                              hipStream_t stream) {
    const float* flow = (const float*)d_in[0];
    float* out = (float*)d_out;   // doubles as a packed buffer until step 7
    float* ws  = (float*)d_ws;    // packed buffer (3*NVOX floats = 59 MB)

    const float inv128 = 1.0f / 128.0f;  // 1 / 2^TIME_STEP

    diffeo_step_t<false, true><<<NBLK, 256, 0, stream>>>(flow, out, inv128); // 1
    diffeo_step_t<true,  true><<<NBLK, 256, 0, stream>>>(out, ws, 1.0f);     // 2
    diffeo_step_t<true,  true><<<NBLK, 256, 0, stream>>>(ws, out, 1.0f);     // 3
    diffeo_step_t<true,  true><<<NBLK, 256, 0, stream>>>(out, ws, 1.0f);     // 4
    diffeo_step_t<true,  true><<<NBLK, 256, 0, stream>>>(ws, out, 1.0f);     // 5
    diffeo_step_t<true,  true><<<NBLK, 256, 0, stream>>>(out, ws, 1.0f);     // 6
    diffeo_step_t<true, false><<<NBLK, 256, 0, stream>>>(ws, out, 1.0f);     // 7
}